// Round 4
// baseline (58.322 us; speedup 1.0000x reference)
//
#include <hip/hip_runtime.h>
#include <math.h>

#define NP 512
#define NS 512
#define DD 512
#define INV64 0.015625f
#define NEGBIG -1000000000.0f
#define LOG2E 1.4426950408889634f

// ws float-slot offsets
#define WS_SLOTBF 0         // 8*512*512 bf16 -> 1048576 float slots
#define WS_WQBF   1048576   // 512*512 bf16
#define WS_WKBF   1179648
#define WS_MTBF   1310720
#define WS_WV     1441792   // 512
#define WS_U      1442304   // 512
#define WS_WQBK   1442816   // 512
#define WS_WKBQ   1443328   // 512
#define WS_VV     1443840   // 4096
#define WS_A      1447936   // 4096
#define WS_E      1452032   // 4096
#define WS_CP     1456128   // 4096
#define WS_CS     1460224   // 4096
#define WS_TV     1464320   // 4096
#define WS_SC     1468416   // [0]=bv.wv [1]=bo.Wval+bval [2]=bq.bk

#define OUT_SCORES 0
#define OUT_VALUE  2097152
#define OUT_COMP   2097160

typedef short bf16x8 __attribute__((ext_vector_type(8)));
typedef float f32x4 __attribute__((ext_vector_type(4)));

__device__ __forceinline__ short f2bf(float f) {
  unsigned u = __builtin_bit_cast(unsigned, f);
  u += 0x7fffu + ((u >> 16) & 1u);
  return (short)(u >> 16);
}

__device__ __forceinline__ void async_copy16(const void* g, void* l) {
  __builtin_amdgcn_global_load_lds(
      (const __attribute__((address_space(1))) unsigned int*)g,
      (__attribute__((address_space(3))) unsigned int*)l, 16, 0, 0);
}

__device__ __forceinline__ float dot8(float4 a0, float4 a1, float4 b0, float4 b1) {
  return a0.x * b0.x + a0.y * b0.y + a0.z * b0.z + a0.w * b0.w +
         a1.x * b1.x + a1.y * b1.y + a1.z * b1.z + a1.w * b1.w;
}

__device__ __forceinline__ float wave_red(float s) {
#pragma unroll
  for (int o = 32; o; o >>= 1) s += __shfl_xor(s, o);
  return s;
}

__device__ inline float wave_dot512(const float* __restrict__ x,
                                    const float* __restrict__ y, int lane) {
  float4 x0 = *(const float4*)&x[lane * 8];
  float4 x1 = *(const float4*)&x[lane * 8 + 4];
  float4 y0 = *(const float4*)&y[lane * 8];
  float4 y1 = *(const float4*)&y[lane * 8 + 4];
  return wave_red(dot8(x0, x1, y0, y1));
}

// ---------------- kA: pre1 row-dots + Wq/Wk -> bf16 convert ----------------
__global__ __launch_bounds__(256) void kA(
    const float* __restrict__ Wo, const float* __restrict__ Wval,
    const float* __restrict__ Wq, const float* __restrict__ bk,
    const float* __restrict__ Wk, const float* __restrict__ bq,
    const float* __restrict__ bo, const float* __restrict__ bval,
    float* __restrict__ ws, short* __restrict__ wqb, short* __restrict__ wkb) {
  int blk = blockIdx.x;
  if (blk < 385) {
    int wid = blk * 4 + (threadIdx.x >> 6);
    int lane = threadIdx.x & 63;
    if (wid >= 1538) return;
    const float *x, *y;
    float* dst;
    float extra = 0.f;
    int r = wid & 511;
    if (wid < 512)       { x = Wo + (size_t)r * DD; y = Wval; dst = ws + WS_WV + r; }
    else if (wid < 1024) { x = Wq + (size_t)r * DD; y = bk;   dst = ws + WS_WQBK + r; }
    else if (wid < 1536) { x = Wk + (size_t)r * DD; y = bq;   dst = ws + WS_WKBQ + r; }
    else if (wid == 1536){ x = bo; y = Wval; dst = ws + WS_SC + 1; extra = *bval; }
    else                 { x = bq; y = bk;   dst = ws + WS_SC + 2; }
    float s = wave_dot512(x, y, lane);
    if (lane == 0) *dst = s + extra;
  } else {
    int t = (blk - 385) * 256 + threadIdx.x;  // 0..65535
    const float* src;
    short* dst;
    int off;
    if (t < 32768) { src = Wq; dst = wqb; off = t * 8; }
    else           { src = Wk; dst = wkb; off = (t - 32768) * 8; }
    float4 v0 = *(const float4*)&src[off];
    float4 v1 = *(const float4*)&src[off + 4];
    bf16x8 o;
    o[0] = f2bf(v0.x); o[1] = f2bf(v0.y); o[2] = f2bf(v0.z); o[3] = f2bf(v0.w);
    o[4] = f2bf(v1.x); o[5] = f2bf(v1.y); o[6] = f2bf(v1.z); o[7] = f2bf(v1.w);
    *(bf16x8*)&dst[off] = o;
  }
}

// stage NG granules (16B) of a [rows][512] bf16 tile into LDS, XOR-swizzled (4-wave)
template <int NG>
__device__ __forceinline__ void stage_tile4(const short* __restrict__ G,
                                            short* lds, int r0, int k0, int wave,
                                            int lane) {
#pragma unroll
  for (int h = 0; h < NG / 256; ++h) {
    int s = h * 256 + wave * 64 + lane;
    int row = s >> 2;
    int g = (s & 3) ^ ((row >> 1) & 3);
    async_copy16(G + (size_t)(r0 + row) * DD + k0 + g * 8,
                 lds + (size_t)(h * 256 + wave * 64) * 8);
  }
}

// ---------------- kB: u = Wv.wv, c0, and MT = Wk_bf . Wq_bf^T (4-wave MFMA) ---
__global__ __launch_bounds__(256) void kB(
    const float* __restrict__ Wv, const float* __restrict__ bv,
    const short* __restrict__ wkb, const short* __restrict__ wqb,
    float* __restrict__ ws, short* __restrict__ mtb) {
  __shared__ short As[2][128 * 32];
  __shared__ short Bs[2][64 * 32];
  if (blockIdx.x < 129) {
    int wid = blockIdx.x * 4 + (threadIdx.x >> 6);
    if (wid >= 513) return;
    int lane = threadIdx.x & 63;
    const float* wv = ws + WS_WV;
    const float *x, *y;
    float* dst;
    if (wid < 512) { x = Wv + (size_t)wid * DD; y = wv; dst = ws + WS_U + wid; }
    else           { x = bv; y = wv; dst = ws + WS_SC + 0; }
    float s = wave_dot512(x, y, lane);
    if (lane == 0) *dst = s;
    return;
  }
  int gb = blockIdx.x - 129;  // 0..31
  const int m0 = (gb & 3) * 128, n0 = (gb >> 2) * 64;
  const int wave = threadIdx.x >> 6, lane = threadIdx.x & 63;
  const int wr = wave >> 1, wc = wave & 1;
  const int li = lane & 15, g = lane >> 4;
  f32x4 acc[4][2] = {};
  stage_tile4<512>(wkb, &As[0][0], m0, 0, wave, lane);
  stage_tile4<256>(wqb, &Bs[0][0], n0, 0, wave, lane);
  __syncthreads();
  int buf = 0;
  for (int k0 = 0; k0 < DD; k0 += 32) {
    if (k0 + 32 < DD) {
      stage_tile4<512>(wkb, &As[buf ^ 1][0], m0, k0 + 32, wave, lane);
      stage_tile4<256>(wqb, &Bs[buf ^ 1][0], n0, k0 + 32, wave, lane);
    }
    bf16x8 af[4], bfr[2];
#pragma unroll
    for (int am = 0; am < 4; ++am) {
      int row = wr * 64 + am * 16 + li;
      int gp = g ^ ((row >> 1) & 3);
      af[am] = *(const bf16x8*)&As[buf][row * 32 + gp * 8];
    }
#pragma unroll
    for (int bn = 0; bn < 2; ++bn) {
      int row = wc * 32 + bn * 16 + li;
      int gp = g ^ ((row >> 1) & 3);
      bfr[bn] = *(const bf16x8*)&Bs[buf][row * 32 + gp * 8];
    }
#pragma unroll
    for (int am = 0; am < 4; ++am)
#pragma unroll
      for (int bn = 0; bn < 2; ++bn)
        acc[am][bn] = __builtin_amdgcn_mfma_f32_16x16x32_bf16(
            af[am], bfr[bn], acc[am][bn], 0, 0, 0);
    __syncthreads();
    buf ^= 1;
  }
#pragma unroll
  for (int am = 0; am < 4; ++am)
#pragma unroll
    for (int i = 0; i < 4; ++i) {
      int grow = m0 + wr * 64 + am * 16 + g * 4 + i;
#pragma unroll
      for (int bn = 0; bn < 2; ++bn) {
        int gcol = n0 + wc * 32 + bn * 16 + li;
        mtb[(size_t)grow * DD + gcol] = f2bf(acc[am][bn][i]);
      }
    }
}

// ---------------- kC: piece/slot prep (bf16 cvt + fused row-dots) ------------
__global__ __launch_bounds__(256) void kC(
    const float* __restrict__ piece, const float* __restrict__ slot,
    const float* __restrict__ Wc, float* __restrict__ ws,
    short* __restrict__ pbf, short* __restrict__ sbf) {
  int lane = threadIdx.x & 63;
  if (blockIdx.x < 1024) {
    int wid = blockIdx.x * 4 + (threadIdx.x >> 6);  // 0..4095
    const float* row = piece + (size_t)wid * DD;
    float4 x0 = *(const float4*)&row[lane * 8];
    float4 x1 = *(const float4*)&row[lane * 8 + 4];
    bf16x8 o;
    o[0] = f2bf(x0.x); o[1] = f2bf(x0.y); o[2] = f2bf(x0.z); o[3] = f2bf(x0.w);
    o[4] = f2bf(x1.x); o[5] = f2bf(x1.y); o[6] = f2bf(x1.z); o[7] = f2bf(x1.w);
    *(bf16x8*)&pbf[(size_t)wid * DD + lane * 8] = o;
    const float* y = ws + WS_WQBK;
    float4 y0 = *(const float4*)&y[lane * 8];
    float4 y1 = *(const float4*)&y[lane * 8 + 4];
    float4 c0 = *(const float4*)&Wc[lane * 8];
    float4 c1 = *(const float4*)&Wc[lane * 8 + 4];
    float da = wave_red(dot8(x0, x1, y0, y1));
    float dc = wave_red(dot8(x0, x1, c0, c1));
    if (lane == 0) { ws[WS_A + wid] = da; ws[WS_CP + wid] = dc; }
  } else {
    int wid = (blockIdx.x - 1024) * 4 + (threadIdx.x >> 6);  // 0..4095
    const float* row = slot + (size_t)wid * DD;
    float4 x0 = *(const float4*)&row[lane * 8];
    float4 x1 = *(const float4*)&row[lane * 8 + 4];
    bf16x8 o;
    o[0] = f2bf(x0.x); o[1] = f2bf(x0.y); o[2] = f2bf(x0.z); o[3] = f2bf(x0.w);
    o[4] = f2bf(x1.x); o[5] = f2bf(x1.y); o[6] = f2bf(x1.z); o[7] = f2bf(x1.w);
    *(bf16x8*)&sbf[(size_t)wid * DD + lane * 8] = o;
    const float* y = ws + WS_WKBQ;
    float4 y0 = *(const float4*)&y[lane * 8];
    float4 y1 = *(const float4*)&y[lane * 8 + 4];
    const float* u = ws + WS_U;
    float4 u0 = *(const float4*)&u[lane * 8];
    float4 u1 = *(const float4*)&u[lane * 8 + 4];
    const float* c = Wc + DD;
    float4 c0 = *(const float4*)&c[lane * 8];
    float4 c1 = *(const float4*)&c[lane * 8 + 4];
    float de = wave_red(dot8(x0, x1, y0, y1));
    float dv = wave_red(dot8(x0, x1, u0, u1));
    float dc = wave_red(dot8(x0, x1, c0, c1));
    if (lane == 0) {
      ws[WS_E + wid] = de;
      ws[WS_VV + wid] = dv + ws[WS_SC + 0];
      ws[WS_CS + wid] = dc;
    }
  }
}

// ---------- kT: T = pbf[4096,512] . mtb[512,512]^T, 8 waves, XCD-swizzled ----
// 1-D grid 256: m = id&31 (so the 8 blocks sharing an A-slice land on one XCD)
__global__ __launch_bounds__(512) void kT(const short* __restrict__ A,
                                          const short* __restrict__ B,
                                          short* __restrict__ Cb) {
  __shared__ short As[2][128 * 32];
  __shared__ short Bs[2][64 * 32];
  const int wave = threadIdx.x >> 6, lane = threadIdx.x & 63;
  const int wr = wave >> 1, wc = wave & 1;
  const int li = lane & 15, g = lane >> 4;
  const int m0 = (blockIdx.x & 31) * 128, n0 = (blockIdx.x >> 5) * 64;
  f32x4 acc[2][2] = {};

  auto stage = [&](int bufi, int k0) {
    int s = wave * 64 + lane;
    int row = s >> 2;
    int gg = (s & 3) ^ ((row >> 1) & 3);
    async_copy16(A + (size_t)(m0 + row) * DD + k0 + gg * 8,
                 &As[bufi][(wave * 64) * 8]);
    if (wave < 4) {
      async_copy16(B + (size_t)(n0 + row) * DD + k0 + gg * 8,
                   &Bs[bufi][(wave * 64) * 8]);
    }
  };

  stage(0, 0);
  __syncthreads();
  int buf = 0;
  for (int k0 = 0; k0 < DD; k0 += 32) {
    if (k0 + 32 < DD) stage(buf ^ 1, k0 + 32);
    bf16x8 af[2], bfv[2];
#pragma unroll
    for (int am = 0; am < 2; ++am) {
      int row = wr * 32 + am * 16 + li;
      int gp = g ^ ((row >> 1) & 3);
      af[am] = *(const bf16x8*)&As[buf][row * 32 + gp * 8];
    }
#pragma unroll
    for (int bn = 0; bn < 2; ++bn) {
      int row = wc * 32 + bn * 16 + li;
      int gp = g ^ ((row >> 1) & 3);
      bfv[bn] = *(const bf16x8*)&Bs[buf][row * 32 + gp * 8];
    }
#pragma unroll
    for (int am = 0; am < 2; ++am)
#pragma unroll
      for (int bn = 0; bn < 2; ++bn)
        acc[am][bn] = __builtin_amdgcn_mfma_f32_16x16x32_bf16(
            af[am], bfv[bn], acc[am][bn], 0, 0, 0);
    __syncthreads();
    buf ^= 1;
  }
#pragma unroll
  for (int am = 0; am < 2; ++am)
#pragma unroll
    for (int i = 0; i < 4; ++i) {
      int grow = m0 + wr * 32 + am * 16 + g * 4 + i;
#pragma unroll
      for (int bn = 0; bn < 2; ++bn) {
        int gcol = n0 + wc * 32 + bn * 16 + li;
        Cb[(size_t)grow * DD + gcol] = f2bf(acc[am][bn][i]);
      }
    }
}

// ---- kS: fused scores row-block GEMM + epilogue + softmax + tv --------------
// 1-D grid 256: b = id&7 (batch -> XCD), m0 = (id>>3)*16. 8 waves; each wave
// owns a 64-col window of the full 512-col row. B-tile (512x32) thru LDS.
__global__ __launch_bounds__(512) void kS(const short* __restrict__ T,
                                          const short* __restrict__ S,
                                          const float* __restrict__ ws,
                                          const float* __restrict__ sbias,
                                          const int* __restrict__ maskp,
                                          float* __restrict__ out,
                                          float* __restrict__ tv) {
  __shared__ short As[2][16 * 32];
  __shared__ short Bs[2][512 * 32];
  __shared__ float redmax[8][16];
  __shared__ float2 redzw[8][16];
  const int id = blockIdx.x;
  const int b = id & 7;
  const int m0 = (id >> 3) * 16;
  const int wave = threadIdx.x >> 6, lane = threadIdx.x & 63;
  const int li = lane & 15, g = lane >> 4;
  const short* Ab = T + ((size_t)b * NP + m0) * DD;
  const short* Bb = S + (size_t)b * NS * DD;
  f32x4 acc[4] = {};

  auto stage = [&](int bufi, int k0) {
#pragma unroll
    for (int h = 0; h < 4; ++h) {
      int s = h * 512 + wave * 64 + lane;
      int row = s >> 2;
      int gg = (s & 3) ^ ((row >> 1) & 3);
      async_copy16(Bb + (size_t)row * DD + k0 + gg * 8,
                   &Bs[bufi][(h * 512 + wave * 64) * 8]);
    }
    if (wave == 0) {
      int row = lane >> 2;
      int gg = (lane & 3) ^ ((row >> 1) & 3);
      async_copy16(Ab + (size_t)row * DD + k0 + gg * 8, &As[bufi][0]);
    }
  };

  stage(0, 0);
  __syncthreads();
  int buf = 0;
  for (int k0 = 0; k0 < DD; k0 += 32) {
    if (k0 + 32 < DD) stage(buf ^ 1, k0 + 32);
    int agp = g ^ ((li >> 1) & 3);
    bf16x8 af = *(const bf16x8*)&As[buf][li * 32 + agp * 8];
    bf16x8 bfv[4];
#pragma unroll
    for (int bn = 0; bn < 4; ++bn) {
      int row = wave * 64 + bn * 16 + li;
      int gp = g ^ ((row >> 1) & 3);
      bfv[bn] = *(const bf16x8*)&Bs[buf][row * 32 + gp * 8];
    }
#pragma unroll
    for (int bn = 0; bn < 4; ++bn)
      acc[bn] = __builtin_amdgcn_mfma_f32_16x16x32_bf16(af, bfv[bn], acc[bn], 0, 0, 0);
    __syncthreads();
    buf ^= 1;
  }

  // ---- epilogue: scores write + fused softmax/tv ----
  const float sbb = ws[WS_SC + 2];
  const float* avp = ws + WS_A + b * NP + m0;
  const float* evp = ws + WS_E + b * NS;
  const float* vvp = ws + WS_VV + b * NS;
  float av[4], sc[4][4], vvl[4];
#pragma unroll
  for (int i = 0; i < 4; ++i) av[i] = avp[g * 4 + i] + sbb;
#pragma unroll
  for (int bn = 0; bn < 4; ++bn) {
    int s = wave * 64 + bn * 16 + li;
    float ev = evp[s];
    vvl[bn] = vvp[s];
#pragma unroll
    for (int i = 0; i < 4; ++i) {
      int p = m0 + g * 4 + i;
      size_t idx = ((size_t)b * NP + p) * NS + s;
      float v = fmaf(acc[bn][i] + av[i] + ev, INV64, sbias[idx]);
      v = (maskp[idx] == 0) ? NEGBIG : v;
      sc[bn][i] = v;
      out[OUT_SCORES + idx] = v;
    }
  }
  float rmax[4];
#pragma unroll
  for (int i = 0; i < 4; ++i)
    rmax[i] = fmaxf(fmaxf(sc[0][i], sc[1][i]), fmaxf(sc[2][i], sc[3][i]));
#pragma unroll
  for (int o = 1; o < 16; o <<= 1)
#pragma unroll
    for (int i = 0; i < 4; ++i) rmax[i] = fmaxf(rmax[i], __shfl_xor(rmax[i], o));
  if (li == 0) {
#pragma unroll
    for (int i = 0; i < 4; ++i) redmax[wave][g * 4 + i] = rmax[i];
  }
  __syncthreads();
  float gmax[4];
#pragma unroll
  for (int i = 0; i < 4; ++i) {
    float m = redmax[0][g * 4 + i];
#pragma unroll
    for (int w = 1; w < 8; ++w) m = fmaxf(m, redmax[w][g * 4 + i]);
    gmax[i] = m;
  }
  float z[4] = {}, wsum[4] = {};
#pragma unroll
  for (int bn = 0; bn < 4; ++bn)
#pragma unroll
    for (int i = 0; i < 4; ++i) {
      float e = exp2f((sc[bn][i] - gmax[i]) * LOG2E);
      z[i] += e;
      wsum[i] += e * vvl[bn];
    }
#pragma unroll
  for (int o = 1; o < 16; o <<= 1)
#pragma unroll
    for (int i = 0; i < 4; ++i) {
      z[i] += __shfl_xor(z[i], o);
      wsum[i] += __shfl_xor(wsum[i], o);
    }
  if (li == 0) {
#pragma unroll
    for (int i = 0; i < 4; ++i)
      redzw[wave][g * 4 + i] = make_float2(z[i], wsum[i]);
  }
  __syncthreads();
  if (wave == 0 && li == 0) {
#pragma unroll
    for (int i = 0; i < 4; ++i) {
      float zt = 0.f, wt = 0.f;
#pragma unroll
      for (int w = 0; w < 8; ++w) {
        float2 v = redzw[w][g * 4 + i];
        zt += v.x;
        wt += v.y;
      }
      tv[b * NP + m0 + g * 4 + i] = (wt / zt) * (1.0f / NP);
    }
  }
}

// ---------------- kG: compatibility write + value reduce ---------------------
__global__ __launch_bounds__(256) void kG(const float* __restrict__ ws,
                                          const float* __restrict__ bc,
                                          float* __restrict__ out) {
  if (blockIdx.x < 2048) {
    int idx = blockIdx.x * 256 + threadIdx.x;
    int lin = idx << 2;
    int s = lin & (NS - 1);
    int p = (lin >> 9) & (NP - 1);
    int bb = lin >> 18;
    float cp = ws[WS_CP + bb * NP + p];
    float4 cs = *(const float4*)&ws[WS_CS + bb * NS + s];
    float bcv = *bc;
    float4 o = make_float4(cp + cs.x + bcv, cp + cs.y + bcv, cp + cs.z + bcv,
                           cp + cs.w + bcv);
    *(float4*)&out[OUT_COMP + lin] = o;
  } else {
    int wave = threadIdx.x >> 6, lane = threadIdx.x & 63;
    int bb = wave * 2 + (lane >> 5);
    int l32 = lane & 31;
    const float* tv = ws + WS_TV + bb * NP;
    float s = 0.f;
#pragma unroll
    for (int k = 0; k < 16; ++k) s += tv[k * 32 + l32];
#pragma unroll
    for (int o = 16; o; o >>= 1) s += __shfl_xor(s, o);
    if (l32 == 0) out[OUT_VALUE + bb] = s + ws[WS_SC + 1];
  }
}

extern "C" void kernel_launch(void* const* d_in, const int* in_sizes, int n_in,
                              void* d_out, int out_size, void* d_ws,
                              size_t ws_size, hipStream_t stream) {
  const float* piece = (const float*)d_in[0];
  const float* slot = (const float*)d_in[1];
  const int* mask = (const int*)d_in[2];
  const float* sbias = (const float*)d_in[3];
  const float* Wq = (const float*)d_in[4];
  const float* bq = (const float*)d_in[5];
  const float* Wk = (const float*)d_in[6];
  const float* bk = (const float*)d_in[7];
  const float* Wv = (const float*)d_in[8];
  const float* bv = (const float*)d_in[9];
  const float* Wo = (const float*)d_in[10];
  const float* bo = (const float*)d_in[11];
  const float* Wc = (const float*)d_in[12];
  const float* bc = (const float*)d_in[13];
  const float* Wval = (const float*)d_in[14];
  const float* bval = (const float*)d_in[15];
  float* out = (float*)d_out;
  float* ws = (float*)d_ws;

  short* pbf = (short*)out;               // piece bf16 in scores region (consumed by kT)
  short* tbf = (short*)(out + OUT_COMP);  // T bf16 in comp region (consumed by kS)
  short* sbf = (short*)(ws + WS_SLOTBF);
  short* wqb = (short*)(ws + WS_WQBF);
  short* wkb = (short*)(ws + WS_WKBF);
  short* mtb = (short*)(ws + WS_MTBF);

  hipLaunchKernelGGL(kA, dim3(641), dim3(256), 0, stream,
                     Wo, Wval, Wq, bk, Wk, bq, bo, bval, ws, wqb, wkb);
  hipLaunchKernelGGL(kB, dim3(161), dim3(256), 0, stream, Wv, bv, wkb, wqb, ws, mtb);
  hipLaunchKernelGGL(kC, dim3(2048), dim3(256), 0, stream, piece, slot, Wc, ws, pbf, sbf);
  hipLaunchKernelGGL(kT, dim3(256), dim3(512), 0, stream, pbf, mtb, tbf);
  hipLaunchKernelGGL(kS, dim3(256), dim3(512), 0, stream, tbf, sbf, ws, sbias, mask,
                     out, ws + WS_TV);
  hipLaunchKernelGGL(kG, dim3(2049), dim3(256), 0, stream, ws, bc, out);
}

// Round 5
// 52.861 us; speedup vs baseline: 1.1033x; 1.1033x over previous
//
#include <hip/hip_runtime.h>
#include <math.h>

#define NP 512
#define NS 512
#define DD 512
#define INV64 0.015625f
#define NEGBIG -1000000000.0f
#define LOG2E 1.4426950408889634f

// ws float-slot offsets
#define WS_SLOTBF 0         // 8*512*512 bf16 -> 1048576 float slots
#define WS_WQBF   1048576   // 512*512 bf16
#define WS_WKBF   1179648
#define WS_MTBF   1310720
#define WS_WV     1441792   // 512
#define WS_U      1442304   // 512
#define WS_WQBK   1442816   // 512
#define WS_WKBQ   1443328   // 512
#define WS_VV     1443840   // 4096
#define WS_A      1447936   // 4096
#define WS_E      1452032   // 4096
#define WS_CP     1456128   // 4096
#define WS_CS     1460224   // 4096
#define WS_Z      1464320   // 4096 softmax partial denom
#define WS_W      1468416   // 4096 softmax partial weighted num
#define WS_SC     1472512   // [0]=bv.wv [1]=bo.Wval+bval [2]=bq.bk

#define OUT_SCORES 0
#define OUT_VALUE  2097152
#define OUT_COMP   2097160

typedef short bf16x8 __attribute__((ext_vector_type(8)));
typedef float f32x4 __attribute__((ext_vector_type(4)));

__device__ __forceinline__ short f2bf(float f) {
  unsigned u = __builtin_bit_cast(unsigned, f);
  u += 0x7fffu + ((u >> 16) & 1u);
  return (short)(u >> 16);
}

__device__ __forceinline__ void async_copy16(const void* g, void* l) {
  __builtin_amdgcn_global_load_lds(
      (const __attribute__((address_space(1))) unsigned int*)g,
      (__attribute__((address_space(3))) unsigned int*)l, 16, 0, 0);
}

__device__ __forceinline__ float dot8(float4 a0, float4 a1, float4 b0, float4 b1) {
  return a0.x * b0.x + a0.y * b0.y + a0.z * b0.z + a0.w * b0.w +
         a1.x * b1.x + a1.y * b1.y + a1.z * b1.z + a1.w * b1.w;
}

__device__ __forceinline__ float wave_red(float s) {
#pragma unroll
  for (int o = 32; o; o >>= 1) s += __shfl_xor(s, o);
  return s;
}

__device__ inline float wave_dot512(const float* __restrict__ x,
                                    const float* __restrict__ y, int lane) {
  float4 x0 = *(const float4*)&x[lane * 8];
  float4 x1 = *(const float4*)&x[lane * 8 + 4];
  float4 y0 = *(const float4*)&y[lane * 8];
  float4 y1 = *(const float4*)&y[lane * 8 + 4];
  return wave_red(dot8(x0, x1, y0, y1));
}

// ---------------- kA: pre1 row-dots + Wq/Wk -> bf16 convert ----------------
__global__ __launch_bounds__(256) void kA(
    const float* __restrict__ Wo, const float* __restrict__ Wval,
    const float* __restrict__ Wq, const float* __restrict__ bk,
    const float* __restrict__ Wk, const float* __restrict__ bq,
    const float* __restrict__ bo, const float* __restrict__ bval,
    float* __restrict__ ws, short* __restrict__ wqb, short* __restrict__ wkb) {
  int blk = blockIdx.x;
  if (blk < 385) {
    int wid = blk * 4 + (threadIdx.x >> 6);
    int lane = threadIdx.x & 63;
    if (wid >= 1538) return;
    const float *x, *y;
    float* dst;
    float extra = 0.f;
    int r = wid & 511;
    if (wid < 512)       { x = Wo + (size_t)r * DD; y = Wval; dst = ws + WS_WV + r; }
    else if (wid < 1024) { x = Wq + (size_t)r * DD; y = bk;   dst = ws + WS_WQBK + r; }
    else if (wid < 1536) { x = Wk + (size_t)r * DD; y = bq;   dst = ws + WS_WKBQ + r; }
    else if (wid == 1536){ x = bo; y = Wval; dst = ws + WS_SC + 1; extra = *bval; }
    else                 { x = bq; y = bk;   dst = ws + WS_SC + 2; }
    float s = wave_dot512(x, y, lane);
    if (lane == 0) *dst = s + extra;
  } else {
    int t = (blk - 385) * 256 + threadIdx.x;  // 0..65535
    const float* src;
    short* dst;
    int off;
    if (t < 32768) { src = Wq; dst = wqb; off = t * 8; }
    else           { src = Wk; dst = wkb; off = (t - 32768) * 8; }
    float4 v0 = *(const float4*)&src[off];
    float4 v1 = *(const float4*)&src[off + 4];
    bf16x8 o;
    o[0] = f2bf(v0.x); o[1] = f2bf(v0.y); o[2] = f2bf(v0.z); o[3] = f2bf(v0.w);
    o[4] = f2bf(v1.x); o[5] = f2bf(v1.y); o[6] = f2bf(v1.z); o[7] = f2bf(v1.w);
    *(bf16x8*)&dst[off] = o;
  }
}

// stage NG granules (16B) of a [rows][512] bf16 tile into LDS, XOR-swizzled (4-wave)
template <int NG>
__device__ __forceinline__ void stage_tile4(const short* __restrict__ G,
                                            short* lds, int r0, int k0, int wave,
                                            int lane) {
#pragma unroll
  for (int h = 0; h < NG / 256; ++h) {
    int s = h * 256 + wave * 64 + lane;
    int row = s >> 2;
    int g = (s & 3) ^ ((row >> 1) & 3);
    async_copy16(G + (size_t)(r0 + row) * DD + k0 + g * 8,
                 lds + (size_t)(h * 256 + wave * 64) * 8);
  }
}

// ---------------- kB: u = Wv.wv, c0, and MT = Wk_bf . Wq_bf^T (4-wave MFMA) ---
__global__ __launch_bounds__(256) void kB(
    const float* __restrict__ Wv, const float* __restrict__ bv,
    const short* __restrict__ wkb, const short* __restrict__ wqb,
    float* __restrict__ ws, short* __restrict__ mtb) {
  __shared__ short As[2][128 * 32];
  __shared__ short Bs[2][64 * 32];
  if (blockIdx.x < 129) {
    int wid = blockIdx.x * 4 + (threadIdx.x >> 6);
    if (wid >= 513) return;
    int lane = threadIdx.x & 63;
    const float* wv = ws + WS_WV;
    const float *x, *y;
    float* dst;
    if (wid < 512) { x = Wv + (size_t)wid * DD; y = wv; dst = ws + WS_U + wid; }
    else           { x = bv; y = wv; dst = ws + WS_SC + 0; }
    float s = wave_dot512(x, y, lane);
    if (lane == 0) *dst = s;
    return;
  }
  int gb = blockIdx.x - 129;  // 0..31
  const int m0 = (gb & 3) * 128, n0 = (gb >> 2) * 64;
  const int wave = threadIdx.x >> 6, lane = threadIdx.x & 63;
  const int wr = wave >> 1, wc = wave & 1;
  const int li = lane & 15, g = lane >> 4;
  f32x4 acc[4][2] = {};
  stage_tile4<512>(wkb, &As[0][0], m0, 0, wave, lane);
  stage_tile4<256>(wqb, &Bs[0][0], n0, 0, wave, lane);
  __syncthreads();
  int buf = 0;
  for (int k0 = 0; k0 < DD; k0 += 32) {
    if (k0 + 32 < DD) {
      stage_tile4<512>(wkb, &As[buf ^ 1][0], m0, k0 + 32, wave, lane);
      stage_tile4<256>(wqb, &Bs[buf ^ 1][0], n0, k0 + 32, wave, lane);
    }
    bf16x8 af[4], bfr[2];
#pragma unroll
    for (int am = 0; am < 4; ++am) {
      int row = wr * 64 + am * 16 + li;
      int gp = g ^ ((row >> 1) & 3);
      af[am] = *(const bf16x8*)&As[buf][row * 32 + gp * 8];
    }
#pragma unroll
    for (int bn = 0; bn < 2; ++bn) {
      int row = wc * 32 + bn * 16 + li;
      int gp = g ^ ((row >> 1) & 3);
      bfr[bn] = *(const bf16x8*)&Bs[buf][row * 32 + gp * 8];
    }
#pragma unroll
    for (int am = 0; am < 4; ++am)
#pragma unroll
      for (int bn = 0; bn < 2; ++bn)
        acc[am][bn] = __builtin_amdgcn_mfma_f32_16x16x32_bf16(
            af[am], bfr[bn], acc[am][bn], 0, 0, 0);
    __syncthreads();
    buf ^= 1;
  }
#pragma unroll
  for (int am = 0; am < 4; ++am)
#pragma unroll
    for (int i = 0; i < 4; ++i) {
      int grow = m0 + wr * 64 + am * 16 + g * 4 + i;
#pragma unroll
      for (int bn = 0; bn < 2; ++bn) {
        int gcol = n0 + wc * 32 + bn * 16 + li;
        mtb[(size_t)grow * DD + gcol] = f2bf(acc[am][bn][i]);
      }
    }
}

// ------- kC: piece/slot prep (bf16 cvt + fused row-dots) + z/w zeroing -------
__global__ __launch_bounds__(256) void kC(
    const float* __restrict__ piece, const float* __restrict__ slot,
    const float* __restrict__ Wc, float* __restrict__ ws,
    short* __restrict__ pbf, short* __restrict__ sbf) {
  int lane = threadIdx.x & 63;
  if (blockIdx.x < 1024) {
    int wid = blockIdx.x * 4 + (threadIdx.x >> 6);  // 0..4095
    const float* row = piece + (size_t)wid * DD;
    float4 x0 = *(const float4*)&row[lane * 8];
    float4 x1 = *(const float4*)&row[lane * 8 + 4];
    bf16x8 o;
    o[0] = f2bf(x0.x); o[1] = f2bf(x0.y); o[2] = f2bf(x0.z); o[3] = f2bf(x0.w);
    o[4] = f2bf(x1.x); o[5] = f2bf(x1.y); o[6] = f2bf(x1.z); o[7] = f2bf(x1.w);
    *(bf16x8*)&pbf[(size_t)wid * DD + lane * 8] = o;
    const float* y = ws + WS_WQBK;
    float4 y0 = *(const float4*)&y[lane * 8];
    float4 y1 = *(const float4*)&y[lane * 8 + 4];
    float4 c0 = *(const float4*)&Wc[lane * 8];
    float4 c1 = *(const float4*)&Wc[lane * 8 + 4];
    float da = wave_red(dot8(x0, x1, y0, y1));
    float dc = wave_red(dot8(x0, x1, c0, c1));
    if (lane == 0) { ws[WS_A + wid] = da; ws[WS_CP + wid] = dc; }
  } else if (blockIdx.x < 2048) {
    int wid = (blockIdx.x - 1024) * 4 + (threadIdx.x >> 6);  // 0..4095
    const float* row = slot + (size_t)wid * DD;
    float4 x0 = *(const float4*)&row[lane * 8];
    float4 x1 = *(const float4*)&row[lane * 8 + 4];
    bf16x8 o;
    o[0] = f2bf(x0.x); o[1] = f2bf(x0.y); o[2] = f2bf(x0.z); o[3] = f2bf(x0.w);
    o[4] = f2bf(x1.x); o[5] = f2bf(x1.y); o[6] = f2bf(x1.z); o[7] = f2bf(x1.w);
    *(bf16x8*)&sbf[(size_t)wid * DD + lane * 8] = o;
    const float* y = ws + WS_WKBQ;
    float4 y0 = *(const float4*)&y[lane * 8];
    float4 y1 = *(const float4*)&y[lane * 8 + 4];
    const float* u = ws + WS_U;
    float4 u0 = *(const float4*)&u[lane * 8];
    float4 u1 = *(const float4*)&u[lane * 8 + 4];
    const float* c = Wc + DD;
    float4 c0 = *(const float4*)&c[lane * 8];
    float4 c1 = *(const float4*)&c[lane * 8 + 4];
    float de = wave_red(dot8(x0, x1, y0, y1));
    float dv = wave_red(dot8(x0, x1, u0, u1));
    float dc = wave_red(dot8(x0, x1, c0, c1));
    if (lane == 0) {
      ws[WS_E + wid] = de;
      ws[WS_VV + wid] = dv + ws[WS_SC + 0];
      ws[WS_CS + wid] = dc;
    }
  } else {
    // zero softmax accumulators (ws is poisoned, not re-poisoned between calls)
    float4 zz = make_float4(0.f, 0.f, 0.f, 0.f);
#pragma unroll
    for (int k = 0; k < 8; ++k)
      *(float4*)&ws[WS_Z + (threadIdx.x * 8 + k) * 4] = zz;
  }
}

// ------ 8-wave GEMM, tile 128x64, BK=64, XOR-swizzled LDS, XCD-pinned -------
// MODE 0 (kT): C = pbf . mtb^T, store bf16.  m0=(id&31)*128, n0=(id>>5)*64.
// MODE 1 (kS): scores epilogue + no-max softmax partials. b=id&7.
template <int MODE>
__global__ __launch_bounds__(512) void k_gemm8(
    const short* __restrict__ A, const short* __restrict__ B,
    short* __restrict__ Cb, const float* __restrict__ ws_,
    const float* __restrict__ sbias, const int* __restrict__ maskp,
    float* __restrict__ out, float* __restrict__ zarr,
    float* __restrict__ warr) {
  __shared__ short As[2][128 * 64];
  __shared__ short Bs[2][64 * 64];
  const int wave = threadIdx.x >> 6, lane = threadIdx.x & 63;
  const int wr = wave >> 1, wc = wave & 1;
  const int li = lane & 15, g = lane >> 4;
  const int id = blockIdx.x;
  int b, m0, n0;
  if (MODE == 0) { b = 0; m0 = (id & 31) * 128; n0 = (id >> 5) * 64; }
  else           { b = id & 7; m0 = ((id >> 3) & 3) * 128; n0 = (id >> 5) * 64; }
  const short* Ab = A + (size_t)b * NP * DD;
  const short* Bb = B + (size_t)b * NS * DD;
  f32x4 acc[2][2] = {};

  auto stage = [&](int bufi, int k0) {
#pragma unroll
    for (int h = 0; h < 2; ++h) {
      int s = h * 512 + wave * 64 + lane;
      int row = s >> 3;
      int gsrc = (s & 7) ^ (row & 7);
      async_copy16(Ab + (size_t)(m0 + row) * DD + k0 + gsrc * 8,
                   &As[bufi][(h * 512 + wave * 64) * 8]);
    }
    {
      int s = wave * 64 + lane;
      int row = s >> 3;
      int gsrc = (s & 7) ^ (row & 7);
      async_copy16(Bb + (size_t)(n0 + row) * DD + k0 + gsrc * 8,
                   &Bs[bufi][(wave * 64) * 8]);
    }
  };

  stage(0, 0);
  __syncthreads();
  int buf = 0;
  for (int k0 = 0; k0 < DD; k0 += 64) {
    if (k0 + 64 < DD) stage(buf ^ 1, k0 + 64);
    bf16x8 af[2][2], bfv[2][2];
#pragma unroll
    for (int kk = 0; kk < 2; ++kk) {
#pragma unroll
      for (int am = 0; am < 2; ++am) {
        int row = wr * 32 + am * 16 + li;
        int slot = row * 8 + ((kk * 4 + g) ^ (row & 7));
        af[am][kk] = *(const bf16x8*)&As[buf][slot * 8];
      }
#pragma unroll
      for (int bn = 0; bn < 2; ++bn) {
        int row = wc * 32 + bn * 16 + li;
        int slot = row * 8 + ((kk * 4 + g) ^ (row & 7));
        bfv[bn][kk] = *(const bf16x8*)&Bs[buf][slot * 8];
      }
    }
#pragma unroll
    for (int kk = 0; kk < 2; ++kk)
#pragma unroll
      for (int am = 0; am < 2; ++am)
#pragma unroll
        for (int bn = 0; bn < 2; ++bn)
          acc[am][bn] = __builtin_amdgcn_mfma_f32_16x16x32_bf16(
              af[am][kk], bfv[bn][kk], acc[am][bn], 0, 0, 0);
    __syncthreads();
    buf ^= 1;
  }

  if (MODE == 0) {
#pragma unroll
    for (int am = 0; am < 2; ++am)
#pragma unroll
      for (int i = 0; i < 4; ++i) {
        int grow = m0 + wr * 32 + am * 16 + g * 4 + i;
#pragma unroll
        for (int bn = 0; bn < 2; ++bn) {
          int gcol = n0 + wc * 32 + bn * 16 + li;
          Cb[(size_t)grow * DD + gcol] = f2bf(acc[am][bn][i]);
        }
      }
  } else {
    const float sbb = ws_[WS_SC + 2];
    const float* evp = ws_ + WS_E + b * NS;
    const float* vvp = ws_ + WS_VV + b * NS;
    const float* avp = ws_ + WS_A + b * NP;
    float ev[2], vvl[2];
#pragma unroll
    for (int bn = 0; bn < 2; ++bn) {
      int scol = n0 + wc * 32 + bn * 16 + li;
      ev[bn] = evp[scol];
      vvl[bn] = vvp[scol];
    }
#pragma unroll
    for (int am = 0; am < 2; ++am)
#pragma unroll
      for (int i = 0; i < 4; ++i) {
        int p = m0 + wr * 32 + am * 16 + g * 4 + i;
        float av = avp[p] + sbb;
        float zp = 0.f, wp = 0.f;
#pragma unroll
        for (int bn = 0; bn < 2; ++bn) {
          int scol = n0 + wc * 32 + bn * 16 + li;
          size_t idx = ((size_t)b * NP + p) * NS + scol;
          float v = fmaf(acc[am][bn][i] + av + ev[bn], INV64, sbias[idx]);
          v = (maskp[idx] == 0) ? NEGBIG : v;
          out[OUT_SCORES + idx] = v;
          float e = exp2f(v * LOG2E);  // masked -> exp2(-1.4e9) = 0 exactly
          zp += e;
          wp += e * vvl[bn];
        }
#pragma unroll
        for (int o = 1; o < 16; o <<= 1) {
          zp += __shfl_xor(zp, o);
          wp += __shfl_xor(wp, o);
        }
        if (li == 0) {
          atomicAdd(&zarr[b * NP + p], zp);
          atomicAdd(&warr[b * NP + p], wp);
        }
      }
  }
}

// -------- kG: compatibility write + value = (1/NP) sum_p w/z + c1 ------------
__global__ __launch_bounds__(256) void kG(const float* __restrict__ ws,
                                          const float* __restrict__ bc,
                                          float* __restrict__ out) {
  if (blockIdx.x < 2048) {
    int idx = blockIdx.x * 256 + threadIdx.x;
    int lin = idx << 2;
    int s = lin & (NS - 1);
    int p = (lin >> 9) & (NP - 1);
    int bb = lin >> 18;
    float cp = ws[WS_CP + bb * NP + p];
    float4 cs = *(const float4*)&ws[WS_CS + bb * NS + s];
    float bcv = *bc;
    float4 o = make_float4(cp + cs.x + bcv, cp + cs.y + bcv, cp + cs.z + bcv,
                           cp + cs.w + bcv);
    *(float4*)&out[OUT_COMP + lin] = o;
  } else {
    int tid = threadIdx.x;
    int bb = tid >> 5, j = tid & 31;
    const float* zp = ws + WS_Z + bb * NP;
    const float* wp = ws + WS_W + bb * NP;
    float s = 0.f;
#pragma unroll
    for (int k = 0; k < 16; ++k) {
      int p = k * 32 + j;
      s += wp[p] / zp[p];
    }
#pragma unroll
    for (int o = 16; o; o >>= 1) s += __shfl_xor(s, o);
    if (j == 0) out[OUT_VALUE + bb] = s * (1.0f / NP) + ws[WS_SC + 1];
  }
}

extern "C" void kernel_launch(void* const* d_in, const int* in_sizes, int n_in,
                              void* d_out, int out_size, void* d_ws,
                              size_t ws_size, hipStream_t stream) {
  const float* piece = (const float*)d_in[0];
  const float* slot = (const float*)d_in[1];
  const int* mask = (const int*)d_in[2];
  const float* sbias = (const float*)d_in[3];
  const float* Wq = (const float*)d_in[4];
  const float* bq = (const float*)d_in[5];
  const float* Wk = (const float*)d_in[6];
  const float* bk = (const float*)d_in[7];
  const float* Wv = (const float*)d_in[8];
  const float* bv = (const float*)d_in[9];
  const float* Wo = (const float*)d_in[10];
  const float* bo = (const float*)d_in[11];
  const float* Wc = (const float*)d_in[12];
  const float* bc = (const float*)d_in[13];
  const float* Wval = (const float*)d_in[14];
  const float* bval = (const float*)d_in[15];
  float* out = (float*)d_out;
  float* ws = (float*)d_ws;

  short* pbf = (short*)out;               // piece bf16 in scores region (consumed by kT)
  short* tbf = (short*)(out + OUT_COMP);  // T bf16 in comp region (consumed by kS)
  short* sbf = (short*)(ws + WS_SLOTBF);
  short* wqb = (short*)(ws + WS_WQBF);
  short* wkb = (short*)(ws + WS_WKBF);
  short* mtb = (short*)(ws + WS_MTBF);

  hipLaunchKernelGGL(kA, dim3(641), dim3(256), 0, stream,
                     Wo, Wval, Wq, bk, Wk, bq, bo, bval, ws, wqb, wkb);
  hipLaunchKernelGGL(kB, dim3(161), dim3(256), 0, stream, Wv, bv, wkb, wqb, ws, mtb);
  hipLaunchKernelGGL(kC, dim3(2049), dim3(256), 0, stream, piece, slot, Wc, ws, pbf, sbf);
  // T = pbf . mtb^T
  hipLaunchKernelGGL((k_gemm8<0>), dim3(256), dim3(512), 0, stream,
                     pbf, mtb, tbf, (const float*)nullptr, (const float*)nullptr,
                     (const int*)nullptr, (float*)nullptr, (float*)nullptr,
                     (float*)nullptr);
  // scores = tbf . sbf^T + epilogue + fused no-max softmax partials
  hipLaunchKernelGGL((k_gemm8<1>), dim3(256), dim3(512), 0, stream,
                     tbf, sbf, (short*)nullptr, ws, sbias, mask, out,
                     ws + WS_Z, ws + WS_W);
  hipLaunchKernelGGL(kG, dim3(2049), dim3(256), 0, stream, ws, bc, out);
}